// Round 3
// baseline (893.667 us; speedup 1.0000x reference)
//
#include <hip/hip_runtime.h>

typedef unsigned int uint;

#define N_NODES 100000
#define N_EDGES 1600000
#define NB_SCAN 391          // ceil(N_NODES/256)

// ---------------------------------------------------------------- bf16 helpers
__device__ __forceinline__ float bflo(uint v) { return __uint_as_float(v << 16); }
__device__ __forceinline__ float bfhi(uint v) { return __uint_as_float(v & 0xffff0000u); }
__device__ __forceinline__ uint packbf2(float a, float b) {   // RNE pack (a->lo, b->hi)
    uint ua = __float_as_uint(a), ub = __float_as_uint(b);
    ua += 0x7fffu + ((ua >> 16) & 1u);
    ub += 0x7fffu + ((ub >> 16) & 1u);
    return (ua >> 16) | (ub & 0xffff0000u);
}

// ---------------------------------------------------------------- graph prep

__global__ void deg_kernel(const int* __restrict__ dst, int* __restrict__ deg) {
    int e = blockIdx.x * blockDim.x + threadIdx.x;
    if (e < N_EDGES) atomicAdd(&deg[dst[e]], 1);
}

__global__ void scan_blocksum(const int* __restrict__ deg, int* __restrict__ blk) {
    __shared__ int s[256];
    int i = blockIdx.x * 256 + threadIdx.x;
    s[threadIdx.x] = (i < N_NODES) ? deg[i] : 0;
    __syncthreads();
    for (int off = 128; off > 0; off >>= 1) {
        if (threadIdx.x < off) s[threadIdx.x] += s[threadIdx.x + off];
        __syncthreads();
    }
    if (threadIdx.x == 0) blk[blockIdx.x] = s[0];
}

__global__ void scan_blockoff(int* __restrict__ blk, int* __restrict__ row_ptr_last) {
    __shared__ int s[512];
    int t = threadIdx.x;
    int v = (t < NB_SCAN) ? blk[t] : 0;
    s[t] = v;
    __syncthreads();
    for (int off = 1; off < 512; off <<= 1) {
        int xv = (t >= off) ? s[t - off] : 0;
        __syncthreads();
        s[t] += xv;
        __syncthreads();
    }
    if (t < NB_SCAN) blk[t] = s[t] - v;           // exclusive
    if (t == NB_SCAN - 1) *row_ptr_last = s[t];   // total = N_EDGES
}

__global__ void scan_final(const int* __restrict__ deg, const int* __restrict__ blk,
                           int* __restrict__ row_ptr, int* __restrict__ cursor) {
    __shared__ int s[256];
    int i = blockIdx.x * 256 + threadIdx.x;
    int v = (i < N_NODES) ? deg[i] : 0;
    s[threadIdx.x] = v;
    __syncthreads();
    for (int off = 1; off < 256; off <<= 1) {
        int xv = (threadIdx.x >= off) ? s[threadIdx.x - off] : 0;
        __syncthreads();
        s[threadIdx.x] += xv;
        __syncthreads();
    }
    if (i < N_NODES) {
        int ex = blk[blockIdx.x] + s[threadIdx.x] - v;
        row_ptr[i] = ex;
        cursor[i]  = ex;
    }
}

__global__ void fill_csr(const int* __restrict__ src, const int* __restrict__ dst,
                         int* __restrict__ cursor, int* __restrict__ colx) {
    int e = blockIdx.x * blockDim.x + threadIdx.x;
    if (e < N_EDGES) {
        int pos = atomicAdd(&cursor[dst[e]], 1);
        colx[pos] = src[e];
    }
}

__global__ void invdeg_kernel(const int* __restrict__ deg, float* __restrict__ invd) {
    int i = blockIdx.x * blockDim.x + threadIdx.x;
    if (i < N_NODES) invd[i] = 1.0f / fmaxf((float)deg[i], 1.0f);
}

// ---------------------------------------------------------------- transform
// out2[row][q] = packed bf16x2 of (relu(h*scale+shift)) or plain cast if scale==null.
// One thread per 4 channels.
__global__ void transform_bf16(const float* __restrict__ H,
                               const float* __restrict__ scale, const float* __restrict__ shift,
                               uint* __restrict__ out2) {
    int i = blockIdx.x * blockDim.x + threadIdx.x;
    if (i >= N_NODES * 32) return;
    int row = i >> 5, q = i & 31;
    float4 v = *(const float4*)(H + (size_t)row * 128 + q * 4);
    if (scale) {
        int c = q * 4;
        v.x = fmaxf(v.x * scale[c]     + shift[c],     0.f);
        v.y = fmaxf(v.y * scale[c + 1] + shift[c + 1], 0.f);
        v.z = fmaxf(v.z * scale[c + 2] + shift[c + 2], 0.f);
        v.w = fmaxf(v.w * scale[c + 3] + shift[c + 3], 0.f);
    }
    uint2 o;
    o.x = packbf2(v.x, v.y);
    o.y = packbf2(v.z, v.w);
    *(uint2*)(out2 + (size_t)row * 64 + q * 2) = o;
}

// ---------------------------------------------------------------- aggregation
// one wave per node; lane holds channels (2*lane, 2*lane+1) as one packed uint.
// unroll-4 over neighbors for memory-level parallelism (latency-bound gather).
__global__ void aggregate_bf16(const uint* __restrict__ H2,
                               const int* __restrict__ row_ptr, const int* __restrict__ colx,
                               const float* __restrict__ invd, uint* __restrict__ agg2) {
    int lane = threadIdx.x & 63;
    int node = blockIdx.x * 4 + (threadIdx.x >> 6);
    if (node >= N_NODES) return;
    int beg = row_ptr[node], end = row_ptr[node + 1];
    float a0 = 0.f, a1 = 0.f;
    int j = beg;
    for (; j + 4 <= end; j += 4) {
        int s0 = colx[j], s1 = colx[j + 1], s2 = colx[j + 2], s3 = colx[j + 3];
        uint v0 = H2[(size_t)s0 * 64 + lane];
        uint v1 = H2[(size_t)s1 * 64 + lane];
        uint v2 = H2[(size_t)s2 * 64 + lane];
        uint v3 = H2[(size_t)s3 * 64 + lane];
        a0 += bflo(v0) + bflo(v1) + bflo(v2) + bflo(v3);
        a1 += bfhi(v0) + bfhi(v1) + bfhi(v2) + bfhi(v3);
    }
    for (; j < end; ++j) {
        uint v = H2[(size_t)colx[j] * 64 + lane];
        a0 += bflo(v);
        a1 += bfhi(v);
    }
    float id = invd[node];
    agg2[(size_t)node * 64 + lane] = packbf2(a0 * id, a1 * id);
}

// ---------------------------------------------------------------- fused conv
// Out[r][c] = A[r] @ Wself + Agg[r] @ Wneigh + bias, A/Agg are packed-bf16 [N][64] uints
// (A is ALREADY transformed). Optionally accumulates per-channel sum/sumsq into stats.
template <int OUTC, bool STATS>
__global__ __launch_bounds__(256) void conv_mm(
    const uint* __restrict__ Aself2, const uint* __restrict__ Agg2,
    const float* __restrict__ Wself, const float* __restrict__ Wneigh,
    const float* __restrict__ bias,
    float* __restrict__ Out, float* __restrict__ stats) {
    constexpr int BM = 64, BK = 32;
    constexpr int TXN = OUTC / 4;      // threads across cols
    constexpr int TY  = 256 / TXN;     // row groups
    constexpr int RPT = BM / TY;       // rows per thread (8 for OUTC=128, 4 for 64)
    __shared__ float At[BK][BM + 4];   // transposed A tile
    __shared__ float Wt[BK][OUTC];

    const int tid = threadIdx.x;
    const int tx = tid % TXN, ty = tid / TXN;
    const int row0 = blockIdx.x * BM;

    float acc[RPT][4];
#pragma unroll
    for (int i = 0; i < RPT; ++i)
#pragma unroll
        for (int j = 0; j < 4; ++j) acc[i][j] = 0.f;

    const int lrow = tid & 63;     // A-load row within tile
    const int lq   = tid >> 6;     // 0..3 (8-channel group within 32-wide K slab)
    const int grow = row0 + lrow;
    const bool rowok = grow < N_NODES;

    for (int step = 0; step < 8; ++step) {
        const int k0 = (step & 3) * BK;
        const bool selfhalf = (step < 4);
        const uint*  Asrc = selfhalf ? Aself2 : Agg2;
        const float* Wsrc = selfhalf ? Wself : Wneigh;

        // ---- load A tile: thread loads uint4 = 8 bf16 channels [k0+lq*8, +8)
        uint4 v = make_uint4(0u, 0u, 0u, 0u);
        if (rowok) v = *(const uint4*)(Asrc + (size_t)grow * 64 + (k0 >> 1) + lq * 4);
        {
            float f[8] = { bflo(v.x), bfhi(v.x), bflo(v.y), bfhi(v.y),
                           bflo(v.z), bfhi(v.z), bflo(v.w), bfhi(v.w) };
#pragma unroll
            for (int t = 0; t < 8; ++t) At[lq * 8 + t][lrow] = f[t];
        }
        // ---- load W tile (flat contiguous copy, f32)
        constexpr int WQ = BK * OUTC / 4 / 256;
#pragma unroll
        for (int h = 0; h < WQ; ++h) {
            int idx = h * 256 + tid;
            ((float4*)&Wt[0][0])[idx] = *(const float4*)(Wsrc + (size_t)k0 * OUTC + (size_t)idx * 4);
        }
        __syncthreads();
#pragma unroll
        for (int kk = 0; kk < BK; ++kk) {
            float4 w = *(const float4*)&Wt[kk][tx * 4];
            float a[RPT];
#pragma unroll
            for (int h = 0; h < RPT / 4; ++h) {
                float4 av = *(const float4*)&At[kk][ty * RPT + h * 4];
                a[h * 4 + 0] = av.x; a[h * 4 + 1] = av.y;
                a[h * 4 + 2] = av.z; a[h * 4 + 3] = av.w;
            }
#pragma unroll
            for (int i = 0; i < RPT; ++i) {
                acc[i][0] += a[i] * w.x;
                acc[i][1] += a[i] * w.y;
                acc[i][2] += a[i] * w.z;
                acc[i][3] += a[i] * w.w;
            }
        }
        __syncthreads();
    }

    // ---- epilogue: bias, store, optional BN stats
    float4 b4 = *(const float4*)(bias + tx * 4);
    float s[4] = {0, 0, 0, 0}, q[4] = {0, 0, 0, 0};
#pragma unroll
    for (int i = 0; i < RPT; ++i) {
        int r = row0 + ty * RPT + i;
        if (r < N_NODES) {
            float4 o;
            o.x = acc[i][0] + b4.x;
            o.y = acc[i][1] + b4.y;
            o.z = acc[i][2] + b4.z;
            o.w = acc[i][3] + b4.w;
            *(float4*)(Out + (size_t)r * OUTC + tx * 4) = o;
            if (STATS) {
                s[0] += o.x; s[1] += o.y; s[2] += o.z; s[3] += o.w;
                q[0] += o.x * o.x; q[1] += o.y * o.y; q[2] += o.z * o.z; q[3] += o.w * o.w;
            }
        }
    }
    if (STATS) {
        float* red = &At[0][0];   // reuse LDS (>= TY*OUTC floats)
        __syncthreads();
#pragma unroll
        for (int j = 0; j < 4; ++j) red[ty * OUTC + tx * 4 + j] = s[j];
        __syncthreads();
        if (ty == 0) {
            float t[4] = {0, 0, 0, 0};
            for (int yy = 0; yy < TY; ++yy)
#pragma unroll
                for (int j = 0; j < 4; ++j) t[j] += red[yy * OUTC + tx * 4 + j];
#pragma unroll
            for (int j = 0; j < 4; ++j) atomicAdd(&stats[tx * 4 + j], t[j]);
        }
        __syncthreads();
#pragma unroll
        for (int j = 0; j < 4; ++j) red[ty * OUTC + tx * 4 + j] = q[j];
        __syncthreads();
        if (ty == 0) {
            float t[4] = {0, 0, 0, 0};
            for (int yy = 0; yy < TY; ++yy)
#pragma unroll
                for (int j = 0; j < 4; ++j) t[j] += red[yy * OUTC + tx * 4 + j];
#pragma unroll
            for (int j = 0; j < 4; ++j) atomicAdd(&stats[OUTC + tx * 4 + j], t[j]);
        }
    }
}

__global__ void bn_finalize(const float* __restrict__ stats,
                            const float* __restrict__ g, const float* __restrict__ be,
                            float* __restrict__ scale, float* __restrict__ shift) {
    int c = threadIdx.x;   // 128
    float mean = stats[c] * (1.0f / N_NODES);
    float var  = stats[128 + c] * (1.0f / N_NODES) - mean * mean;
    float inv  = rsqrtf(var + 1e-5f);
    float sc   = g[c] * inv;
    scale[c] = sc;
    shift[c] = be[c] - mean * sc;
}

__global__ void logsoftmax_k(float* __restrict__ out) {
    int lane = threadIdx.x & 63;
    int row = blockIdx.x * 4 + (threadIdx.x >> 6);
    if (row >= N_NODES) return;
    size_t base = (size_t)row * 64;
    float v = out[base + lane];
    float m = v;
#pragma unroll
    for (int o = 32; o > 0; o >>= 1) m = fmaxf(m, __shfl_xor(m, o));
    float e = expf(v - m);
    float ssum = e;
#pragma unroll
    for (int o = 32; o > 0; o >>= 1) ssum += __shfl_xor(ssum, o);
    out[base + lane] = v - m - logf(ssum);
}

// ---------------------------------------------------------------- launch

extern "C" void kernel_launch(void* const* d_in, const int* in_sizes, int n_in,
                              void* d_out, int out_size, void* d_ws, size_t ws_size,
                              hipStream_t stream) {
    const float* x   = (const float*)d_in[0];
    const int*   ei  = (const int*)d_in[1];
    const float* w0s = (const float*)d_in[2];
    const float* w0n = (const float*)d_in[3];
    const float* b0  = (const float*)d_in[4];
    const float* g0  = (const float*)d_in[5];
    const float* be0 = (const float*)d_in[6];
    const float* w1s = (const float*)d_in[7];
    const float* w1n = (const float*)d_in[8];
    const float* b1  = (const float*)d_in[9];
    const float* g1  = (const float*)d_in[10];
    const float* be1 = (const float*)d_in[11];
    const float* w2s = (const float*)d_in[12];
    const float* w2n = (const float*)d_in[13];
    const float* b2  = (const float*)d_in[14];
    float* out = (float*)d_out;

    const int* src = ei;            // edge_index[0]
    const int* dst = ei + N_EDGES;  // edge_index[1]

    char* w = (char*)d_ws;
    size_t off = 0;
    auto alloc = [&](size_t bytes) {
        void* p = w + off;
        off += (bytes + 255) & ~(size_t)255;
        return p;
    };
    int*   deg     = (int*)alloc(N_NODES * 4);
    int*   row_ptr = (int*)alloc((N_NODES + 1) * 4);
    int*   cursor  = (int*)alloc(N_NODES * 4);
    int*   blk     = (int*)alloc(512 * 4);
    int*   colx    = (int*)alloc((size_t)N_EDGES * 4);
    float* invd    = (float*)alloc(N_NODES * 4);
    float* stats   = (float*)alloc(256 * 4);
    float* scale0  = (float*)alloc(128 * 4);
    float* shift0  = (float*)alloc(128 * 4);
    float* scale1  = (float*)alloc(128 * 4);
    float* shift1  = (float*)alloc(128 * 4);
    uint*  ht2     = (uint*)alloc((size_t)N_NODES * 64 * 4);   // packed bf16 features
    uint*  agg2    = (uint*)alloc((size_t)N_NODES * 64 * 4);   // packed bf16 aggregate
    float* h       = (float*)alloc((size_t)N_NODES * 128 * 4); // f32 conv output

    const int EB    = (N_EDGES + 255) / 256;      // 6250
    const int NBk   = NB_SCAN;                    // 391
    const int CONVG = (N_NODES + 63) / 64;        // 1563
    const int AGGG  = (N_NODES + 3) / 4;          // 25000
    const int TFG   = (N_NODES * 32 + 255) / 256; // 12500

    // graph prep
    hipMemsetAsync(deg, 0, N_NODES * 4, stream);
    deg_kernel<<<EB, 256, 0, stream>>>(dst, deg);
    scan_blocksum<<<NBk, 256, 0, stream>>>(deg, blk);
    scan_blockoff<<<1, 512, 0, stream>>>(blk, row_ptr + N_NODES);
    scan_final<<<NBk, 256, 0, stream>>>(deg, blk, row_ptr, cursor);
    fill_csr<<<EB, 256, 0, stream>>>(src, dst, cursor, colx);
    invdeg_kernel<<<NBk, 256, 0, stream>>>(deg, invd);

    // layer 0: ht2 = bf16(x)
    transform_bf16<<<TFG, 256, 0, stream>>>(x, nullptr, nullptr, ht2);
    aggregate_bf16<<<AGGG, 256, 0, stream>>>(ht2, row_ptr, colx, invd, agg2);
    hipMemsetAsync(stats, 0, 256 * 4, stream);
    conv_mm<128, true><<<CONVG, 256, 0, stream>>>(ht2, agg2, w0s, w0n, b0, h, stats);
    bn_finalize<<<1, 128, 0, stream>>>(stats, g0, be0, scale0, shift0);

    // layer 1: ht2 = bf16(relu(bn(h)))
    transform_bf16<<<TFG, 256, 0, stream>>>(h, scale0, shift0, ht2);
    aggregate_bf16<<<AGGG, 256, 0, stream>>>(ht2, row_ptr, colx, invd, agg2);
    hipMemsetAsync(stats, 0, 256 * 4, stream);
    conv_mm<128, true><<<CONVG, 256, 0, stream>>>(ht2, agg2, w1s, w1n, b1, h, stats);
    bn_finalize<<<1, 128, 0, stream>>>(stats, g1, be1, scale1, shift1);

    // layer 2 + log_softmax
    transform_bf16<<<TFG, 256, 0, stream>>>(h, scale1, shift1, ht2);
    aggregate_bf16<<<AGGG, 256, 0, stream>>>(ht2, row_ptr, colx, invd, agg2);
    conv_mm<64, false><<<CONVG, 256, 0, stream>>>(ht2, agg2, w2s, w2n, b2, out, nullptr);
    logsoftmax_k<<<AGGG, 256, 0, stream>>>(out);
}